// Round 1
// baseline (96.571 us; speedup 1.0000x reference)
//
#include <hip/hip_runtime.h>

// TensorRelaxationPooling: B=8, T=4096, D=128, NB=32, STRIDE=2
//   z1 = X@E + bx   [32768, 32]
//   z2 = X@F + by   [32768, 32]
//   out[p, i*32+j] = 0.5*G*(z1[2p,i]*z2[2p,j] + z1[2p+1,i]*z2[2p+1,j])
// Output 64 MiB fp32 -> write-bound; fuse everything into one kernel.

#define DIN 128
#define NB_ 32

constexpr int N2   = 64;   // z1|z2 concatenated basis dim
constexpr int FR   = 64;   // raw frames per block
constexpr int POOL = 32;   // pooled frames per block
constexpr int SXS  = 132;  // LDS X-tile row stride (floats): 16B-aligned, banks offset by 16
constexpr int SZS  = 68;   // LDS Z row stride (floats): 16B-aligned, +4-bank skew
constexpr int NBLK = (8 * 4096) / FR;  // 512

__global__ __launch_bounds__(256) void trp_fused(
    const float* __restrict__ X, const float* __restrict__ E,
    const float* __restrict__ F, const float* __restrict__ G,
    const float* __restrict__ bx, const float* __restrict__ by,
    float* __restrict__ out)
{
    __shared__ __align__(16) float sw[DIN * N2];   // W[d][n] = [E | F], 32 KB
    __shared__ __align__(16) float sxz[FR * SXS];  // X tile; Z overlays after K-loop. 33 KB

    const int tid = threadIdx.x;
    const int blk = blockIdx.x;

    // --- stage W = [E | F] into LDS: 2048 float4, 8 per thread, coalesced ---
    #pragma unroll
    for (int it = 0; it < 8; ++it) {
        int v = tid + 256 * it;        // float4 index
        int d = v >> 4, c = v & 15;    // row, float4-column of sw
        const float* src = (c < 8) ? (E + d * NB_ + c * 4)
                                   : (F + d * NB_ + (c - 8) * 4);
        float4 val = *(const float4*)src;
        *(float4*)&sw[d * N2 + c * 4] = val;
    }
    // --- stage X tile (64 frames contiguous in global) ---
    const float* xb = X + (size_t)blk * FR * DIN;
    #pragma unroll
    for (int it = 0; it < 8; ++it) {
        int v = tid + 256 * it;
        int f = v >> 5, dc = v & 31;
        float4 val = *(const float4*)(xb + f * DIN + dc * 4);
        *(float4*)&sxz[f * SXS + dc * 4] = val;
    }
    __syncthreads();

    // --- register-tiled GEMM: thread owns 4 frames x 4 basis cols ---
    const int n0 = (tid & 15) * 4;   // basis col base (0..60)
    const int f0 = (tid >> 4) * 4;   // frame base     (0..60)

    float acc[4][4];
    #pragma unroll
    for (int q = 0; q < 4; ++q)
        #pragma unroll
        for (int c = 0; c < 4; ++c) acc[q][c] = 0.f;

    #pragma unroll 2
    for (int dc = 0; dc < DIN / 4; ++dc) {
        const int d4 = dc * 4;
        float w[4][4];
        #pragma unroll
        for (int r = 0; r < 4; ++r)
            *(float4*)&w[r][0] = *(const float4*)&sw[(d4 + r) * N2 + n0];
        #pragma unroll
        for (int q = 0; q < 4; ++q) {
            float x[4];
            *(float4*)&x[0] = *(const float4*)&sxz[(f0 + q) * SXS + d4];
            #pragma unroll
            for (int r = 0; r < 4; ++r)
                #pragma unroll
                for (int c = 0; c < 4; ++c)
                    acc[q][c] = fmaf(x[r], w[r][c], acc[q][c]);
        }
    }

    // --- add bias, overlay Z into the X-tile LDS region ---
    float bias[4];
    if (n0 < NB_) *(float4*)bias = *(const float4*)(bx + n0);
    else          *(float4*)bias = *(const float4*)(by + (n0 - NB_));

    __syncthreads();  // everyone done reading sxz as X before we overwrite as Z
    #pragma unroll
    for (int q = 0; q < 4; ++q) {
        float4 z;
        z.x = acc[q][0] + bias[0];
        z.y = acc[q][1] + bias[1];
        z.z = acc[q][2] + bias[2];
        z.w = acc[q][3] + bias[3];
        *(float4*)&sxz[(f0 + q) * SZS + n0] = z;
    }
    __syncthreads();

    // --- epilogue: outer products + pair-pooling, coalesced float4 stores ---
    // out element group for this thread within a pooled frame: k = 4*tid
    //   i = tid>>3 (row of outer product), j = (tid&7)*4 (col base)
    const float g2 = 0.5f * G[0];
    const int i = tid >> 3;
    const int j = (tid & 7) * 4;
    float4* outv = (float4*)out + (size_t)blk * (POOL * 256) + tid;
    #pragma unroll 4
    for (int p = 0; p < POOL; ++p) {
        const float* zr0 = &sxz[(2 * p) * SZS];
        const float* zr1 = &sxz[(2 * p + 1) * SZS];
        float a0 = zr0[i];                                  // z1 frame 2p,   basis i
        float a1 = zr1[i];                                  // z1 frame 2p+1, basis i
        float4 v0 = *(const float4*)&zr0[NB_ + j];          // z2 frame 2p,   basis j..j+3
        float4 v1 = *(const float4*)&zr1[NB_ + j];          // z2 frame 2p+1
        float4 r;
        r.x = g2 * fmaf(a0, v0.x, a1 * v1.x);
        r.y = g2 * fmaf(a0, v0.y, a1 * v1.y);
        r.z = g2 * fmaf(a0, v0.z, a1 * v1.z);
        r.w = g2 * fmaf(a0, v0.w, a1 * v1.w);
        outv[p * 256] = r;
    }
}

extern "C" void kernel_launch(void* const* d_in, const int* in_sizes, int n_in,
                              void* d_out, int out_size, void* d_ws, size_t ws_size,
                              hipStream_t stream) {
    const float* X  = (const float*)d_in[0];
    const float* E  = (const float*)d_in[1];
    const float* F  = (const float*)d_in[2];
    const float* G  = (const float*)d_in[3];
    const float* bx = (const float*)d_in[4];
    const float* by = (const float*)d_in[5];
    float* out = (float*)d_out;
    trp_fused<<<dim3(NBLK), dim3(256), 0, stream>>>(X, E, F, G, bx, by, out);
}